// Round 1
// baseline (483.970 us; speedup 1.0000x reference)
//
#include <hip/hip_runtime.h>
#include <math.h>

// GraphTransformerLayer on MI355X (gfx950).
// B=8, N=1024, D=512, H=8, Dh=64, F=2048.
// Pipeline: cvt(bf16) -> prep(adjm,rowmax) -> QKV gemm -> v-transpose ->
//           knorm/Cbound -> attn ctx (+1/l) -> attn mean -> Wo+LN1 -> FFN1 -> FFN2+LN2.

using bf16_t = __bf16;
typedef __attribute__((__ext_vector_type__(8))) __bf16 bf16x8;
typedef __attribute__((__ext_vector_type__(4))) __bf16 bf16x4;
typedef __attribute__((__ext_vector_type__(4))) float  f32x4;

#define DEVI __device__ __forceinline__

DEVI f32x4 mfma16(bf16x8 a, bf16x8 b, f32x4 c) {
  return __builtin_amdgcn_mfma_f32_16x16x32_bf16(a, b, c, 0, 0, 0);
}

__constant__ const float kScale = 0.125f;   // 1/sqrt(64)
#define NEGC  (-1.0e9f)
#define EPSC  (1e-5f)

// ---------------- f32 -> bf16 convert (vector4) ----------------
__global__ __launch_bounds__(256) void k_cvt(const float* __restrict__ in,
                                             bf16_t* __restrict__ out, int n4) {
  int i = blockIdx.x * 256 + threadIdx.x;
  if (i < n4) {
    float4 v = ((const float4*)in)[i];
    bf16x4 o = { (__bf16)v.x, (__bf16)v.y, (__bf16)v.z, (__bf16)v.w };
    ((bf16x4*)out)[i] = o;
  }
}

// ---------------- adjm = mask ? adj : NEG ; rowmax of masked adj ----------------
__global__ __launch_bounds__(256) void k_prep(const float* __restrict__ adj,
                                              const int* __restrict__ msk,
                                              float* __restrict__ adjm,
                                              float* __restrict__ rowmax) {
  int row  = blockIdx.x * 4 + (threadIdx.x >> 6);
  int lane = threadIdx.x & 63;
  float m = -INFINITY;
  for (int i = 0; i < 16; i++) {
    int c = lane + 64 * i;
    size_t idx = (size_t)row * 1024 + c;
    float a = adj[idx];
    bool valid = (msk[idx] != 0);
    adjm[idx] = valid ? a : NEGC;
    if (valid) m = fmaxf(m, a);
  }
  for (int off = 1; off < 64; off <<= 1) m = fmaxf(m, __shfl_xor(m, off));
  if (lane == 0) rowmax[row] = m;
}

// ---------------- QKV projection GEMM: [8192x512] x W^T -> q,k,v [8192x512] ----------------
__global__ __launch_bounds__(256) void k_qkv(const bf16_t* __restrict__ xb,
                                             const bf16_t* __restrict__ wq,
                                             const bf16_t* __restrict__ wk,
                                             const bf16_t* __restrict__ wv,
                                             bf16_t* __restrict__ q,
                                             bf16_t* __restrict__ k,
                                             bf16_t* __restrict__ v) {
  int bid = blockIdx.x;
  int mb = bid / 12, nb = bid % 12;
  int tid = threadIdx.x, wid = tid >> 6, lane = tid & 63;
  int l16 = lane & 15, g = lane >> 4;
  int rbase = mb * 128 + (wid >> 1) * 64;
  int cbase = nb * 128 + (wid & 1) * 64;
  int which = cbase >> 9, e0 = cbase & 511;
  const bf16_t* W = (which == 0) ? wq : (which == 1) ? wk : wv;
  bf16_t* O = (which == 0) ? q : (which == 1) ? k : v;

  f32x4 acc[4][4];
#pragma unroll
  for (int m = 0; m < 4; m++)
#pragma unroll
    for (int n = 0; n < 4; n++) acc[m][n] = (f32x4){0.f, 0.f, 0.f, 0.f};

  const bf16_t* Ap = xb + (size_t)(rbase + l16) * 512 + 8 * g;
  const bf16_t* Bp = W + (size_t)(e0 + l16) * 512 + 8 * g;
  for (int k0 = 0; k0 < 512; k0 += 32) {
    bf16x8 af[4], bq[4];
#pragma unroll
    for (int m = 0; m < 4; m++) af[m] = *(const bf16x8*)(Ap + m * 16 * 512 + k0);
#pragma unroll
    for (int n = 0; n < 4; n++) bq[n] = *(const bf16x8*)(Bp + n * 16 * 512 + k0);
#pragma unroll
    for (int m = 0; m < 4; m++)
#pragma unroll
      for (int n = 0; n < 4; n++) acc[m][n] = mfma16(af[m], bq[n], acc[m][n]);
  }
#pragma unroll
  for (int m = 0; m < 4; m++)
#pragma unroll
    for (int n = 0; n < 4; n++)
#pragma unroll
      for (int j = 0; j < 4; j++) {
        int row = rbase + m * 16 + g * 4 + j;
        int col = e0 + n * 16 + l16;
        O[(size_t)row * 512 + col] = (__bf16)acc[m][n][j];
      }
}

// ---------------- v transpose: [B,N,H*64] -> vT [B,H,64,N] ----------------
__global__ __launch_bounds__(256) void k_vtrans(const bf16_t* __restrict__ v,
                                                bf16_t* __restrict__ vT) {
  int bid = blockIdx.x;
  int nt = bid & 15, h = (bid >> 4) & 7, b = bid >> 7;
  __shared__ bf16_t t[64 * 66];
  int tid = threadIdx.x, wid = tid >> 6, lane = tid & 63;
  for (int i = 0; i < 16; i++) {
    int n = wid * 16 + i;
    t[lane * 66 + n] = v[(size_t)(b * 1024 + nt * 64 + n) * 512 + h * 64 + lane];
  }
  __syncthreads();
  for (int i = 0; i < 16; i++) {
    int d = wid * 16 + i;
    vT[(size_t)((b * 8 + h) * 64 + d) * 1024 + nt * 64 + lane] = t[d * 66 + lane];
  }
}

// ---------------- max_n |k[b,h,n,:]| ----------------
__global__ __launch_bounds__(256) void k_knorm(const bf16_t* __restrict__ kk,
                                               float* __restrict__ kmax) {
  int bh = blockIdx.x;
  int b = bh >> 3, h = bh & 7;
  int tid = threadIdx.x;
  float mx = 0.f;
  for (int n = tid; n < 1024; n += 256) {
    const bf16_t* kp = kk + (size_t)(b * 1024 + n) * 512 + h * 64;
    float ss = 0.f;
#pragma unroll
    for (int vv = 0; vv < 8; vv++) {
      bf16x8 kv = *(const bf16x8*)(kp + vv * 8);
#pragma unroll
      for (int e = 0; e < 8; e++) { float f = (float)kv[e]; ss += f * f; }
    }
    mx = fmaxf(mx, ss);
  }
  for (int off = 1; off < 64; off <<= 1) mx = fmaxf(mx, __shfl_xor(mx, off));
  __shared__ float red[4];
  if ((tid & 63) == 0) red[tid >> 6] = mx;
  __syncthreads();
  if (tid == 0) kmax[bh] = sqrtf(fmaxf(fmaxf(red[0], red[1]), fmaxf(red[2], red[3])));
}

// ---------------- score upper bound C[b,h,n] = |q| * kmax / 8 + rowmax(adj) ----------------
__global__ __launch_bounds__(256) void k_cbound(const bf16_t* __restrict__ q,
                                                const float* __restrict__ kmax,
                                                const float* __restrict__ rowmax,
                                                float* __restrict__ Cb) {
  int t = blockIdx.x * 256 + threadIdx.x;  // (b*8+h)*1024 + n
  int b = t >> 13, h = (t >> 10) & 7, n = t & 1023;
  const bf16_t* qp = q + (size_t)(b * 1024 + n) * 512 + h * 64;
  float ss = 0.f;
#pragma unroll
  for (int vv = 0; vv < 8; vv++) {
    bf16x8 kv = *(const bf16x8*)(qp + vv * 8);
#pragma unroll
    for (int e = 0; e < 8; e++) { float f = (float)kv[e]; ss += f * f; }
  }
  float am = rowmax[n];
  Cb[t] = (am < -1e30f) ? 0.f : (sqrtf(ss) * kmax[b * 8 + h] * kScale + am);
}

// ---------------- attention: ctx[b,n,h*64+d] and 1/l ----------------
__global__ __launch_bounds__(256) void k_attn_ctx(const bf16_t* __restrict__ q,
                                                  const bf16_t* __restrict__ kk,
                                                  const bf16_t* __restrict__ vT,
                                                  const float* __restrict__ adjm,
                                                  const float* __restrict__ Cb,
                                                  float* __restrict__ rcpl,
                                                  bf16_t* __restrict__ ctx) {
  __shared__ bf16_t pt[4][16 * 72];
  int bid = blockIdx.x;
  int qt = bid & 15, h = (bid >> 4) & 7, b = bid >> 7;
  int tid = threadIdx.x, wid = tid >> 6, lane = tid & 63;
  int l16 = lane & 15, g = lane >> 4;
  int qg0 = qt * 64 + wid * 16;

  const bf16_t* qp = q + (size_t)(b * 1024 + qg0 + l16) * 512 + h * 64 + 8 * g;
  bf16x8 aq0 = *(const bf16x8*)qp;
  bf16x8 aq1 = *(const bf16x8*)(qp + 32);

  float Cj[4];
#pragma unroll
  for (int j = 0; j < 4; j++) Cj[j] = Cb[(b * 8 + h) * 1024 + qg0 + g * 4 + j];

  f32x4 cacc[4];
#pragma unroll
  for (int d = 0; d < 4; d++) cacc[d] = (f32x4){0.f, 0.f, 0.f, 0.f};
  float ls[4] = {0.f, 0.f, 0.f, 0.f};
  bf16_t* myp = pt[wid];
  int kvbase = (b * 8 + h) * 64;

  for (int kt = 0; kt < 16; kt++) {
    int kc0 = kt * 64;
    __syncthreads();
#pragma unroll
    for (int cg = 0; cg < 4; cg++) {
      const bf16_t* kp = kk + (size_t)(b * 1024 + kc0 + cg * 16 + l16) * 512 + h * 64 + 8 * g;
      f32x4 s = (f32x4){0.f, 0.f, 0.f, 0.f};
      s = mfma16(aq0, *(const bf16x8*)kp, s);
      s = mfma16(aq1, *(const bf16x8*)(kp + 32), s);
#pragma unroll
      for (int j = 0; j < 4; j++) {
        int qr = qg0 + g * 4 + j;
        int kc = kc0 + cg * 16 + l16;
        float sv = s[j] * kScale + adjm[(size_t)qr * 1024 + kc];
        float p = __expf(sv - Cj[j]);
        ls[j] += p;
        myp[(g * 4 + j) * 72 + cg * 16 + l16] = (__bf16)p;
      }
    }
    __syncthreads();
#pragma unroll
    for (int half = 0; half < 2; half++) {
      bf16x8 pa = *(const bf16x8*)(myp + l16 * 72 + half * 32 + 8 * g);
#pragma unroll
      for (int dg = 0; dg < 4; dg++) {
        const bf16_t* vp = vT + (size_t)(kvbase + dg * 16 + l16) * 1024 + kc0 + half * 32 + 8 * g;
        cacc[dg] = mfma16(pa, *(const bf16x8*)vp, cacc[dg]);
      }
    }
  }

#pragma unroll
  for (int j = 0; j < 4; j++)
    for (int off = 1; off < 16; off <<= 1) ls[j] += __shfl_xor(ls[j], off);
  float rc[4];
#pragma unroll
  for (int j = 0; j < 4; j++) rc[j] = (ls[j] > 0.f) ? (1.f / ls[j]) : 0.f;

#pragma unroll
  for (int dg = 0; dg < 4; dg++)
#pragma unroll
    for (int j = 0; j < 4; j++) {
      int row = qg0 + g * 4 + j;
      ctx[(size_t)(b * 1024 + row) * 512 + h * 64 + dg * 16 + l16] = (__bf16)(cacc[dg][j] * rc[j]);
    }
  if (l16 == 0) {
#pragma unroll
    for (int j = 0; j < 4; j++) rcpl[(b * 8 + h) * 1024 + qg0 + g * 4 + j] = rc[j];
  }
}

// ---------------- attention mean over heads -> d_out[4.19M .. ] ----------------
__global__ __launch_bounds__(256) void k_attn_mean(const bf16_t* __restrict__ q,
                                                   const bf16_t* __restrict__ kk,
                                                   const float* __restrict__ adjm,
                                                   const float* __restrict__ Cb,
                                                   const float* __restrict__ rcpl,
                                                   float* __restrict__ mout) {
  int bid = blockIdx.x;
  int qt = bid & 63, b = bid >> 6;
  int tid = threadIdx.x, wid = tid >> 6, lane = tid & 63;
  int l16 = lane & 15, g = lane >> 4;
  int qg0 = qt * 16;

  for (int kt = 0; kt < 4; kt++) {
    int kc0 = wid * 256 + kt * 64;
    float av[4][4];
#pragma unroll
    for (int cg = 0; cg < 4; cg++)
#pragma unroll
      for (int j = 0; j < 4; j++)
        av[cg][j] = adjm[(size_t)(qg0 + g * 4 + j) * 1024 + kc0 + cg * 16 + l16];

    f32x4 macc[4];
#pragma unroll
    for (int cg = 0; cg < 4; cg++) macc[cg] = (f32x4){0.f, 0.f, 0.f, 0.f};

    for (int h = 0; h < 8; h++) {
      const bf16_t* qp = q + (size_t)(b * 1024 + qg0 + l16) * 512 + h * 64 + 8 * g;
      bf16x8 aq0 = *(const bf16x8*)qp;
      bf16x8 aq1 = *(const bf16x8*)(qp + 32);
      float Cj[4], Rj[4];
#pragma unroll
      for (int j = 0; j < 4; j++) {
        int sidx = (b * 8 + h) * 1024 + qg0 + g * 4 + j;
        Cj[j] = Cb[sidx];
        Rj[j] = rcpl[sidx];
      }
#pragma unroll
      for (int cg = 0; cg < 4; cg++) {
        const bf16_t* kp = kk + (size_t)(b * 1024 + kc0 + cg * 16 + l16) * 512 + h * 64 + 8 * g;
        f32x4 s = (f32x4){0.f, 0.f, 0.f, 0.f};
        s = mfma16(aq0, *(const bf16x8*)kp, s);
        s = mfma16(aq1, *(const bf16x8*)(kp + 32), s);
        f32x4 m = macc[cg];
#pragma unroll
        for (int j = 0; j < 4; j++) {
          float sv = s[j] * kScale + av[cg][j];
          m[j] += __expf(sv - Cj[j]) * Rj[j];
        }
        macc[cg] = m;
      }
    }
#pragma unroll
    for (int cg = 0; cg < 4; cg++)
#pragma unroll
      for (int j = 0; j < 4; j++)
        mout[(size_t)(b * 1024 + qg0 + g * 4 + j) * 1024 + kc0 + cg * 16 + l16] =
            macc[cg][j] * 0.125f;
  }
}

// ---------------- FFN1: relu(z @ W1^T + b1) -> [8192 x 2048] bf16 ----------------
__global__ __launch_bounds__(256) void k_ffn1(const bf16_t* __restrict__ zb,
                                              const bf16_t* __restrict__ w1,
                                              const float* __restrict__ b1,
                                              bf16_t* __restrict__ hb) {
  int bid = blockIdx.x;
  int mb = bid >> 4, nb = bid & 15;
  int tid = threadIdx.x, wid = tid >> 6, lane = tid & 63;
  int l16 = lane & 15, g = lane >> 4;
  int rbase = mb * 128 + (wid >> 1) * 64;
  int cbase = nb * 128 + (wid & 1) * 64;

  f32x4 acc[4][4];
#pragma unroll
  for (int m = 0; m < 4; m++)
#pragma unroll
    for (int n = 0; n < 4; n++) acc[m][n] = (f32x4){0.f, 0.f, 0.f, 0.f};

  const bf16_t* Ap = zb + (size_t)(rbase + l16) * 512 + 8 * g;
  const bf16_t* Bp = w1 + (size_t)(cbase + l16) * 512 + 8 * g;
  for (int k0 = 0; k0 < 512; k0 += 32) {
    bf16x8 af[4], bq[4];
#pragma unroll
    for (int m = 0; m < 4; m++) af[m] = *(const bf16x8*)(Ap + m * 16 * 512 + k0);
#pragma unroll
    for (int n = 0; n < 4; n++) bq[n] = *(const bf16x8*)(Bp + n * 16 * 512 + k0);
#pragma unroll
    for (int m = 0; m < 4; m++)
#pragma unroll
      for (int n = 0; n < 4; n++) acc[m][n] = mfma16(af[m], bq[n], acc[m][n]);
  }
#pragma unroll
  for (int n = 0; n < 4; n++) {
    int col = cbase + n * 16 + l16;
    float bv = b1[col];
#pragma unroll
    for (int m = 0; m < 4; m++)
#pragma unroll
      for (int j = 0; j < 4; j++) {
        int row = rbase + m * 16 + g * 4 + j;
        hb[(size_t)row * 2048 + col] = (__bf16)fmaxf(acc[m][n][j] + bv, 0.f);
      }
  }
}

// ---------------- GEMM (32 rows x 512 cols / block) + residual + LayerNorm ----------------
__global__ __launch_bounds__(256) void k_lngemm(const bf16_t* __restrict__ A,
                                                const bf16_t* __restrict__ W, int K,
                                                const float* __restrict__ resid,
                                                const float* __restrict__ bias,
                                                const float* __restrict__ gam,
                                                const float* __restrict__ bet,
                                                float* __restrict__ outf,
                                                bf16_t* __restrict__ outb) {
  __shared__ float sm[32 * 512];
  int bid = blockIdx.x;
  int r0 = bid * 32;
  int tid = threadIdx.x, wid = tid >> 6, lane = tid & 63;
  int l16 = lane & 15, g4 = lane >> 4;
  int cw = wid * 128;

  f32x4 acc[2][8];
#pragma unroll
  for (int m = 0; m < 2; m++)
#pragma unroll
    for (int n = 0; n < 8; n++) acc[m][n] = (f32x4){0.f, 0.f, 0.f, 0.f};

  const bf16_t* Ap = A + (size_t)(r0 + l16) * K + 8 * g4;
  const bf16_t* Bp = W + (size_t)(cw + l16) * K + 8 * g4;
  for (int k0 = 0; k0 < K; k0 += 32) {
    bf16x8 a0 = *(const bf16x8*)(Ap + k0);
    bf16x8 a1 = *(const bf16x8*)(Ap + (size_t)16 * K + k0);
    bf16x8 bq[8];
#pragma unroll
    for (int n = 0; n < 8; n++) bq[n] = *(const bf16x8*)(Bp + (size_t)n * 16 * K + k0);
#pragma unroll
    for (int n = 0; n < 8; n++) {
      acc[0][n] = mfma16(a0, bq[n], acc[0][n]);
      acc[1][n] = mfma16(a1, bq[n], acc[1][n]);
    }
  }

  bool has_bias = (bias != nullptr);
#pragma unroll
  for (int n = 0; n < 8; n++) {
    int c = cw + n * 16 + l16;
    float bv = has_bias ? bias[c] : 0.f;
#pragma unroll
    for (int m = 0; m < 2; m++)
#pragma unroll
      for (int j = 0; j < 4; j++) sm[(m * 16 + g4 * 4 + j) * 512 + c] = acc[m][n][j] + bv;
  }
  __syncthreads();
  for (int idx = tid; idx < 32 * 512; idx += 256) sm[idx] += resid[(size_t)r0 * 512 + idx];
  __syncthreads();

  // LayerNorm: wave handles 8 rows
  for (int rr = 0; rr < 8; rr++) {
    int row = wid * 8 + rr;
    float v[8];
    float s = 0.f;
#pragma unroll
    for (int i = 0; i < 8; i++) { v[i] = sm[row * 512 + lane + 64 * i]; s += v[i]; }
    for (int off = 1; off < 64; off <<= 1) s += __shfl_xor(s, off);
    float mu = s * (1.f / 512.f);
    float sq = 0.f;
#pragma unroll
    for (int i = 0; i < 8; i++) { float d = v[i] - mu; sq += d * d; }
    for (int off = 1; off < 64; off <<= 1) sq += __shfl_xor(sq, off);
    float rs = rsqrtf(sq * (1.f / 512.f) + EPSC);
#pragma unroll
    for (int i = 0; i < 8; i++) {
      int c = lane + 64 * i;
      float o = (v[i] - mu) * rs * gam[c] + bet[c];
      outf[(size_t)(r0 + row) * 512 + c] = o;
      if (outb) outb[(size_t)(r0 + row) * 512 + c] = (__bf16)o;
    }
  }
}

extern "C" void kernel_launch(void* const* d_in, const int* in_sizes, int n_in,
                              void* d_out, int out_size, void* d_ws, size_t ws_size,
                              hipStream_t stream) {
  (void)in_sizes; (void)n_in; (void)out_size; (void)ws_size;
  const float* x   = (const float*)d_in[0];
  const float* adj = (const float*)d_in[1];
  const int*   msk = (const int*)d_in[2];
  const float* Wq  = (const float*)d_in[3];
  const float* Wk  = (const float*)d_in[4];
  const float* Wv  = (const float*)d_in[5];
  const float* Wo  = (const float*)d_in[6];
  const float* W1  = (const float*)d_in[7];
  const float* b1  = (const float*)d_in[8];
  const float* W2  = (const float*)d_in[9];
  const float* b2  = (const float*)d_in[10];
  const float* g1  = (const float*)d_in[11];
  const float* be1 = (const float*)d_in[12];
  const float* g2  = (const float*)d_in[13];
  const float* be2 = (const float*)d_in[14];

  float* out  = (float*)d_out;
  float* mout = out + (size_t)8 * 1024 * 512;

  char* ws = (char*)d_ws;
  const size_t MB = 1024 * 1024;
  bf16_t* wqb = (bf16_t*)(ws);
  bf16_t* wkb = (bf16_t*)(ws + 512 * 1024);
  bf16_t* wvb = (bf16_t*)(ws + 1 * MB);
  bf16_t* wob = (bf16_t*)(ws + 3 * MB / 2);
  bf16_t* w1b = (bf16_t*)(ws + 2 * MB);
  bf16_t* w2b = (bf16_t*)(ws + 4 * MB);
  float*  Cb   = (float*)(ws + 6 * MB);             // 256 KB
  float*  rcpl = (float*)(ws + 6 * MB + 256 * 1024); // 256 KB
  float*  amax = (float*)(ws + 6 * MB + 512 * 1024); // 4 KB
  float*  kmax = (float*)(ws + 6 * MB + 768 * 1024); // 256 B
  bf16_t* xb  = (bf16_t*)(ws + 8 * MB);    // 8 MB; reused as ctx after QKV
  bf16_t* ctx = xb;
  bf16_t* qb  = (bf16_t*)(ws + 16 * MB);   // 8 MB
  bf16_t* kb  = (bf16_t*)(ws + 24 * MB);   // 8 MB
  bf16_t* vb  = (bf16_t*)(ws + 32 * MB);   // 8 MB
  bf16_t* vT  = (bf16_t*)(ws + 40 * MB);   // 8 MB
  bf16_t* hb  = qb;                        // 32 MB, reuses q/k/v/vT after attention
  bf16_t* zb  = (bf16_t*)(ws + 48 * MB);   // 8 MB
  float*  zf  = (float*)(ws + 56 * MB);    // 16 MB
  float*  adjm = (float*)(ws + 72 * MB);   // 4 MB  (total 76 MB)

  // converts
  k_cvt<<<4096, 256, 0, stream>>>(x,  xb,  1048576);
  k_cvt<<<256,  256, 0, stream>>>(Wq, wqb, 65536);
  k_cvt<<<256,  256, 0, stream>>>(Wk, wkb, 65536);
  k_cvt<<<256,  256, 0, stream>>>(Wv, wvb, 65536);
  k_cvt<<<256,  256, 0, stream>>>(Wo, wob, 65536);
  k_cvt<<<1024, 256, 0, stream>>>(W1, w1b, 262144);
  k_cvt<<<1024, 256, 0, stream>>>(W2, w2b, 262144);

  k_prep<<<256, 256, 0, stream>>>(adj, msk, adjm, amax);

  k_qkv<<<768, 256, 0, stream>>>(xb, wqb, wkb, wvb, qb, kb, vb);
  k_vtrans<<<1024, 256, 0, stream>>>(vb, vT);
  k_knorm<<<64, 256, 0, stream>>>(kb, kmax);
  k_cbound<<<256, 256, 0, stream>>>(qb, kmax, amax, Cb);

  k_attn_ctx<<<1024, 256, 0, stream>>>(qb, kb, vT, adjm, Cb, rcpl, ctx);
  k_attn_mean<<<512, 256, 0, stream>>>(qb, kb, adjm, Cb, rcpl, mout);

  // Wo proj + residual + LN1 -> zf (f32) + zb (bf16)
  k_lngemm<<<256, 256, 0, stream>>>(ctx, wob, 512, x, nullptr, g1, be1, zf, zb);
  // FFN1
  k_ffn1<<<1024, 256, 0, stream>>>(zb, w1b, b1, hb);
  // FFN2 + b2 + residual(z) + LN2 -> out
  k_lngemm<<<256, 256, 0, stream>>>(hb, w2b, 2048, zf, b2, g2, be2, out, (bf16_t*)nullptr);
}